// Round 2
// baseline (570.231 us; speedup 1.0000x reference)
//
#include <hip/hip_runtime.h>

// ST_Affine: affine_grid (align_corners=False) + grid_sample bilinear/zeros.
// B=16, C=64, H=W=256, fp32 in/out.
//
// V3: V2's h-coarsening (HB=4) kept, but channel loop split 4-ways across
// blocks to restore parallelism.
//  - V2 post-mortem: FETCH dropped 584->120 MB (theory right) but grid=1024
//    blocks capped occupancy at 36% -> BW collapsed to 1.5 TB/s (latency-bound).
//  - Channel planes are disjoint => C-split duplicates ZERO fetch; per-thread
//    row reuse is per-plane and intact. Grid 1024 -> 4096 blocks.
//  - XCD swizzle keeps vertically-adjacent tiles (shared boundary rows) on
//    the same XCD's L2. NT stores keep the output stream out of L2.

constexpr int B = 16, C = 64, H = 256, W = 256;
constexpr int HW = H * W;        // 65536
constexpr int CHW = C * HW;      // 4194304
constexpr int HB = 4;            // rows per thread
constexpr int CSPLIT = 4;        // channel chunks per tile
constexpr int CPB = C / CSPLIT;  // 16 channels per block
constexpr int NTILE = B * (H / HB);          // 1024 (b,h0) tiles
constexpr int NBLK = NTILE * CSPLIT;         // 4096 blocks, %8 == 0

__global__ __launch_bounds__(256) void st_affine_kernel(
    const float* __restrict__ x, const float* __restrict__ theta,
    float* __restrict__ out)
{
    // XCD-contiguous swizzle: XCD k owns swz in [k*512, (k+1)*512) ->
    // tiles [k*128, (k+1)*128) (contiguous h-ranges -> boundary rows L2-hit).
    const int bid = blockIdx.x;
    constexpr int CHUNK = NBLK / 8;               // 512
    const int swz = (bid & 7) * CHUNK + (bid >> 3);

    const int tile  = swz >> 2;                   // 0..1023
    const int cchunk = swz & 3;                   // 0..3
    const int b  = tile >> 6;                     // tile / (H/HB)
    const int h0 = (tile & 63) * HB;
    const int w  = threadIdx.x;                   // lane = w -> coalesced

    // theta[b, 2, 3] flat: [t00 t01 t02 t10 t11 t12] (wave-uniform scalar loads)
    const float* th = theta + b * 6;
    const float t0 = th[0], t1 = th[1], t2 = th[2];
    const float t3 = th[3], t4 = th[4], t5 = th[5];

    const float gx = (w + 0.5f) * (2.0f / W) - 1.0f;

    float wt[HB][4];
    int   off[HB][4];
#pragma unroll
    for (int hh = 0; hh < HB; ++hh) {
        const float gy = (h0 + hh + 0.5f) * (2.0f / H) - 1.0f;

        const float sx = t0 * gx + t1 * gy + t2;
        const float sy = t3 * gx + t4 * gy + t5;

        const float ix = ((sx + 1.0f) * (float)W - 1.0f) * 0.5f;
        const float iy = ((sy + 1.0f) * (float)H - 1.0f) * 0.5f;

        const float ix0f = floorf(ix);
        const float iy0f = floorf(iy);
        const float tx = ix - ix0f;
        const float ty = iy - iy0f;
        const int ix0 = (int)ix0f, iy0 = (int)iy0f;
        const int ix1 = ix0 + 1,   iy1 = iy0 + 1;

        const float vx0 = (ix0 >= 0 && ix0 < W) ? 1.0f : 0.0f;
        const float vx1 = (ix1 >= 0 && ix1 < W) ? 1.0f : 0.0f;
        const float vy0 = (iy0 >= 0 && iy0 < H) ? 1.0f : 0.0f;
        const float vy1 = (iy1 >= 0 && iy1 < H) ? 1.0f : 0.0f;

        wt[hh][0] = (1.0f - tx) * (1.0f - ty) * vx0 * vy0;
        wt[hh][1] = tx          * (1.0f - ty) * vx1 * vy0;
        wt[hh][2] = (1.0f - tx) * ty          * vx0 * vy1;
        wt[hh][3] = tx          * ty          * vx1 * vy1;

        const int cx0 = min(max(ix0, 0), W - 1);
        const int cx1 = min(max(ix1, 0), W - 1);
        const int cy0 = min(max(iy0, 0), H - 1);
        const int cy1 = min(max(iy1, 0), H - 1);

        off[hh][0] = cy0 * W + cx0;
        off[hh][1] = cy0 * W + cx1;
        off[hh][2] = cy1 * W + cx0;
        off[hh][3] = cy1 * W + cx1;
    }

    const int c0 = cchunk * CPB;
    const float* __restrict__ xb = x + (size_t)b * CHW + (size_t)c0 * HW;
    float* __restrict__ ob = out + (size_t)b * CHW + (size_t)c0 * HW + h0 * W + w;

#pragma unroll 2
    for (int c = 0; c < CPB; ++c) {
        const float* __restrict__ xc = xb + c * HW;
        float* __restrict__ oc = ob + (size_t)c * HW;
#pragma unroll
        for (int hh = 0; hh < HB; ++hh) {
            const float v = xc[off[hh][0]] * wt[hh][0]
                          + xc[off[hh][1]] * wt[hh][1]
                          + xc[off[hh][2]] * wt[hh][2]
                          + xc[off[hh][3]] * wt[hh][3];
            // output is never re-read: bypass L2 allocation
            __builtin_nontemporal_store(v, oc + hh * W);
        }
    }
}

extern "C" void kernel_launch(void* const* d_in, const int* in_sizes, int n_in,
                              void* d_out, int out_size, void* d_ws, size_t ws_size,
                              hipStream_t stream) {
    const float* x     = (const float*)d_in[0];
    const float* theta = (const float*)d_in[1];
    float* out = (float*)d_out;

    dim3 grid(NBLK), block(256);
    st_affine_kernel<<<grid, block, 0, stream>>>(x, theta, out);
}

// Round 3
// 548.680 us; speedup vs baseline: 1.0393x; 1.0393x over previous
//
#include <hip/hip_runtime.h>

// ST_Affine: affine_grid (align_corners=False) + grid_sample bilinear/zeros.
// B=16, C=64, H=W=256, fp32 in/out.
//
// V4: x-corner PAIR loads. V1/V2/V3 all land at ~250-280us despite 2.2x
// different HBM bytes -> VMEM request-path bound (4 scattered dword gathers
// per pixel; shear in theta slants each wave's footprint across ~6 rows).
//  - The two x-corners per row are adjacent floats: load ONE unaligned
//    global_load_dwordx2 per row (gfx950 unaligned-access-mode) instead of
//    two dword gathers. 4 loads/pixel -> 2.
//  - Corner validity + the one-element shift at the x edges (ix0==-1 or
//    ix0==W-1) folds into per-element weights computed once per row, outside
//    the 16-channel loop. Bit-identical products to V3.
//  - Structure otherwise identical to V3: HB=4 row coarsening, 4-way C-split,
//    4096 blocks, XCD-contiguous swizzle, NT stores.

constexpr int B = 16, C = 64, H = 256, W = 256;
constexpr int HW = H * W;        // 65536
constexpr int CHW = C * HW;      // 4194304
constexpr int HB = 4;            // rows per thread
constexpr int CSPLIT = 4;        // channel chunks per tile
constexpr int CPB = C / CSPLIT;  // 16 channels per block
constexpr int NTILE = B * (H / HB);          // 1024 (b,h0) tiles
constexpr int NBLK = NTILE * CSPLIT;         // 4096 blocks, %8 == 0

typedef float f2v __attribute__((ext_vector_type(2)));

__device__ __forceinline__ f2v load2u(const float* p) {
    f2v r;
    __builtin_memcpy(&r, p, sizeof(r));   // 8B load, align 4 -> dwordx2 (unaligned ok)
    return r;
}

__global__ __launch_bounds__(256) void st_affine_kernel(
    const float* __restrict__ x, const float* __restrict__ theta,
    float* __restrict__ out)
{
    const int bid = blockIdx.x;
    constexpr int CHUNK = NBLK / 8;               // 512 blocks per XCD
    const int swz = (bid & 7) * CHUNK + (bid >> 3);

    const int tile   = swz >> 2;                  // 0..1023
    const int cchunk = swz & 3;                   // 0..3
    const int b  = tile >> 6;                     // tile / (H/HB)
    const int h0 = (tile & 63) * HB;
    const int w  = threadIdx.x;                   // lane = w -> coalesced stores

    const float* th = theta + b * 6;
    const float t0 = th[0], t1 = th[1], t2 = th[2];
    const float t3 = th[3], t4 = th[4], t5 = th[5];

    const float gx = (w + 0.5f) * (2.0f / W) - 1.0f;

    // Per row: one pair base per source row (y0 and y1 share x-pair base),
    // and 4 combined weights addressing the 4 loaded pair elements.
    int   offp0[HB], offp1[HB];                   // pair offsets, rows y0/y1
    float qA0[HB], qB0[HB], qA1[HB], qB1[HB];     // weights for p0.x,p0.y,p1.x,p1.y

#pragma unroll
    for (int hh = 0; hh < HB; ++hh) {
        const float gy = (h0 + hh + 0.5f) * (2.0f / H) - 1.0f;

        const float sx = t0 * gx + t1 * gy + t2;
        const float sy = t3 * gx + t4 * gy + t5;

        const float ix = ((sx + 1.0f) * (float)W - 1.0f) * 0.5f;
        const float iy = ((sy + 1.0f) * (float)H - 1.0f) * 0.5f;

        const float ix0f = floorf(ix);
        const float iy0f = floorf(iy);
        const float tx = ix - ix0f;
        const float ty = iy - iy0f;
        const int ix0 = (int)ix0f, iy0 = (int)iy0f;
        const int ix1 = ix0 + 1,   iy1 = iy0 + 1;

        const float vx0 = (ix0 >= 0 && ix0 < W) ? 1.0f : 0.0f;
        const float vx1 = (ix1 >= 0 && ix1 < W) ? 1.0f : 0.0f;
        const float vy0 = (iy0 >= 0 && iy0 < H) ? 1.0f : 0.0f;
        const float vy1 = (iy1 >= 0 && iy1 < H) ? 1.0f : 0.0f;

        // pair base column: always in [0, W-2]; loads are always safe
        const int bx = min(max(ix0, 0), W - 2);

        // map corner x-weights onto pair elements (handles edge shift;
        // out-of-range corners contribute 0 via vx*)
        const float wx0 = (1.0f - tx) * vx0;
        const float wx1 = tx * vx1;
        const float wxA = ((bx     == ix0) ? wx0 : 0.0f) + ((bx     == ix1) ? wx1 : 0.0f);
        const float wxB = ((bx + 1 == ix0) ? wx0 : 0.0f) + ((bx + 1 == ix1) ? wx1 : 0.0f);

        const float wy0 = (1.0f - ty) * vy0;
        const float wy1 = ty * vy1;

        qA0[hh] = wxA * wy0;  qB0[hh] = wxB * wy0;
        qA1[hh] = wxA * wy1;  qB1[hh] = wxB * wy1;

        const int cy0 = min(max(iy0, 0), H - 1);
        const int cy1 = min(max(iy1, 0), H - 1);
        offp0[hh] = cy0 * W + bx;
        offp1[hh] = cy1 * W + bx;
    }

    const int c0 = cchunk * CPB;
    const float* __restrict__ xb = x + (size_t)b * CHW + (size_t)c0 * HW;
    float* __restrict__ ob = out + (size_t)b * CHW + (size_t)c0 * HW + h0 * W + w;

#pragma unroll 2
    for (int c = 0; c < CPB; ++c) {
        const float* __restrict__ xc = xb + c * HW;
        float* __restrict__ oc = ob + (size_t)c * HW;
#pragma unroll
        for (int hh = 0; hh < HB; ++hh) {
            const f2v p0 = load2u(xc + offp0[hh]);   // row y0: (x0,x0+1)
            const f2v p1 = load2u(xc + offp1[hh]);   // row y1
            const float v = p0.x * qA0[hh] + p0.y * qB0[hh]
                          + p1.x * qA1[hh] + p1.y * qB1[hh];
            __builtin_nontemporal_store(v, oc + hh * W);
        }
    }
}

extern "C" void kernel_launch(void* const* d_in, const int* in_sizes, int n_in,
                              void* d_out, int out_size, void* d_ws, size_t ws_size,
                              hipStream_t stream) {
    const float* x     = (const float*)d_in[0];
    const float* theta = (const float*)d_in[1];
    float* out = (float*)d_out;

    dim3 grid(NBLK), block(256);
    st_affine_kernel<<<grid, block, 0, stream>>>(x, theta, out);
}